// Round 4
// baseline (315.513 us; speedup 1.0000x reference)
//
#include <hip/hip_runtime.h>
#include <hip/hip_bf16.h>
#include <math.h>

#define B_  4
#define T_  2048
#define D_  1024
#define H_  16
#define HD_ 64
#define U_  38
#define M_  (B_*T_)   // 8192
#define NCW_ 32       // 64-j chunks per head

typedef __attribute__((ext_vector_type(8))) short bf16x8;
typedef __attribute__((ext_vector_type(4))) float f32x4;

__device__ __forceinline__ short f2b(float f) {
    __hip_bfloat16 b = __float2bfloat16(f);
    return *(short*)&b;
}
__device__ __forceinline__ float b2f(short s) {
    __hip_bfloat16 b = *(__hip_bfloat16*)&s;
    return __bfloat162float(b);
}
__device__ __forceinline__ unsigned pack2(float lo, float hi) {
    unsigned a = (unsigned short)f2b(lo);
    unsigned b = ((unsigned)(unsigned short)f2b(hi)) << 16;
    return a | b;
}

__device__ __forceinline__ void gload16(const void* g, void* l) {
    __builtin_amdgcn_global_load_lds(
        (const __attribute__((address_space(1))) unsigned int*)g,
        (__attribute__((address_space(3))) unsigned int*)l,
        16, 0, 0);
}

// ---------------------------------------------------------------------------
// x [8192][1024] fp32 -> xh, xl bf16 (hi + residual-lo split)
// ---------------------------------------------------------------------------
__global__ __launch_bounds__(256) void convx_kernel(
    const float* __restrict__ x, short* __restrict__ xh, short* __restrict__ xl)
{
    const size_t i = ((size_t)blockIdx.x * 256 + threadIdx.x) * 4;
    float4 v = *(const float4*)(x + i);
    short4 h, l;
    h.x = f2b(v.x); l.x = f2b(v.x - b2f(h.x));
    h.y = f2b(v.y); l.y = f2b(v.y - b2f(h.y));
    h.z = f2b(v.z); l.z = f2b(v.z - b2f(h.z));
    h.w = f2b(v.w); l.w = f2b(v.w - b2f(h.w));
    *(short4*)(xh + i) = h;
    *(short4*)(xl + i) = l;
}

// ---------------------------------------------------------------------------
// Transpose weights to [n][k] bf16. z=0: Wq -> wqh+wql. z=1: Wk. z=2: Wv.
// ---------------------------------------------------------------------------
__global__ __launch_bounds__(256) void convw_kernel(
    const float* __restrict__ Wq, const float* __restrict__ Wk, const float* __restrict__ Wv,
    short* __restrict__ wqh, short* __restrict__ wql, short* __restrict__ wkvt)
{
    __shared__ float tile[32][33];
    const int which = blockIdx.z;
    const float* W = which == 0 ? Wq : (which == 1 ? Wk : Wv);
    const int k0 = blockIdx.y * 32, n0 = blockIdx.x * 32;
    const int tx = threadIdx.x & 31, ty = threadIdx.x >> 5;
    #pragma unroll
    for (int r = ty; r < 32; r += 8)
        tile[r][tx] = W[(size_t)(k0 + r) * D_ + n0 + tx];
    __syncthreads();
    #pragma unroll
    for (int r = ty; r < 32; r += 8) {
        float v = tile[tx][r];                 // W[k0+tx][n0+r]
        size_t o = (size_t)(n0 + r) * D_ + k0 + tx;
        if (which == 0) {
            short h = f2b(v);
            wqh[o] = h;
            wql[o] = f2b(v - b2f(h));
        } else {
            wkvt[(size_t)(which - 1) * D_ * D_ + o] = f2b(v);
        }
    }
}

// ---------------------------------------------------------------------------
// K/V projection. K -> kb [g][t][d]; V -> vt [g][d][t] (transposed, so the
// attention PV step can read V^T fragments contiguously).
// ---------------------------------------------------------------------------
__global__ __launch_bounds__(256) void kv_gemm(
    const short* __restrict__ xh, const short* __restrict__ wkvt,
    const float* __restrict__ bk, const float* __restrict__ bv,
    short* __restrict__ kb, short* __restrict__ vt)
{
    __shared__ short As[128 * 32];
    __shared__ short Bs[128 * 32];
    const int tid = threadIdx.x, wid = tid >> 6, lane = tid & 63;
    const int m0 = blockIdx.x * 128;
    const int n0 = blockIdx.y * 128;
    const int wr = (wid >> 1) * 64, wc = (wid & 1) * 64;

    f32x4 acc[4][4];
    #pragma unroll
    for (int i = 0; i < 4; ++i)
        #pragma unroll
        for (int j = 0; j < 4; ++j)
            acc[i][j] = (f32x4){0.f, 0.f, 0.f, 0.f};

    const int srow = lane >> 2, scol = (lane & 3) * 8;

    for (int k0 = 0; k0 < D_; k0 += 32) {
        #pragma unroll
        for (int cc = 0; cc < 2; ++cc) {
            int c = wid + cc * 4;
            int r = c * 16 + srow;
            gload16(xh   + (size_t)(m0 + r) * D_ + k0 + scol, (char*)As + c * 1024);
            gload16(wkvt + (size_t)(n0 + r) * D_ + k0 + scol, (char*)Bs + c * 1024);
        }
        asm volatile("s_waitcnt vmcnt(0)" ::: "memory");
        __syncthreads();
        bf16x8 a[4], b[4];
        #pragma unroll
        for (int i = 0; i < 4; ++i)
            a[i] = *(bf16x8*)&As[(wr + i * 16 + (lane & 15)) * 32 + (lane >> 4) * 8];
        #pragma unroll
        for (int j = 0; j < 4; ++j)
            b[j] = *(bf16x8*)&Bs[(wc + j * 16 + (lane & 15)) * 32 + (lane >> 4) * 8];
        #pragma unroll
        for (int i = 0; i < 4; ++i)
            #pragma unroll
            for (int j = 0; j < 4; ++j)
                acc[i][j] = __builtin_amdgcn_mfma_f32_16x16x32_bf16(a[i], b[j], acc[i][j], 0, 0, 0);
        __syncthreads();
    }

    #pragma unroll
    for (int i = 0; i < 4; ++i)
        #pragma unroll
        for (int j = 0; j < 4; ++j)
            #pragma unroll
            for (int r = 0; r < 4; ++r) {
                int row = m0 + wr + i * 16 + (lane >> 4) * 4 + r;
                int col = n0 + wc + j * 16 + (lane & 15);
                int bb = row >> 11, t = row & (T_ - 1);
                float bias = (col < D_) ? bk[col] : bv[col - D_];
                float val = acc[i][j][r] + bias;
                int cc2 = col & (D_ - 1);
                int hh = cc2 >> 6, dd = cc2 & 63;
                if (col < D_)
                    kb[(((size_t)bb * H_ + hh) * T_ + t) * HD_ + dd] = f2b(val);
                else
                    vt[(((size_t)bb * H_ + hh) * HD_ + dd) * T_ + t] = f2b(val);
            }
}

// ---------------------------------------------------------------------------
// Q: 3-product split-bf16 GEMM (xh·wh + xh·wl + xl·wh), fp32 acc. Writes
// per-(b,h,t) L1 norm (fp32-accurate, for ranking) and q values (bf16).
// ---------------------------------------------------------------------------
__global__ __launch_bounds__(256) void q_gemm(
    const short* __restrict__ xh, const short* __restrict__ xl,
    const short* __restrict__ wqh, const short* __restrict__ wql,
    const float* __restrict__ bq, float* __restrict__ qnorm,
    short* __restrict__ qbuf)
{
    __shared__ short Ah[128 * 32], Al[128 * 32], Bh[128 * 32], Bl[128 * 32];
    const int tid = threadIdx.x, wid = tid >> 6, lane = tid & 63;
    const int m0 = blockIdx.x * 128;
    const int n0 = blockIdx.y * 128;
    const int wr = (wid >> 1) * 64, wc = (wid & 1) * 64;

    f32x4 acc[4][4];
    #pragma unroll
    for (int i = 0; i < 4; ++i)
        #pragma unroll
        for (int j = 0; j < 4; ++j)
            acc[i][j] = (f32x4){0.f, 0.f, 0.f, 0.f};

    const int srow = lane >> 2, scol = (lane & 3) * 8;

    for (int k0 = 0; k0 < D_; k0 += 32) {
        #pragma unroll
        for (int cc = 0; cc < 2; ++cc) {
            int c = wid + cc * 4;
            int r = c * 16 + srow;
            size_t ao = (size_t)(m0 + r) * D_ + k0 + scol;
            size_t bo = (size_t)(n0 + r) * D_ + k0 + scol;
            gload16(xh  + ao, (char*)Ah + c * 1024);
            gload16(xl  + ao, (char*)Al + c * 1024);
            gload16(wqh + bo, (char*)Bh + c * 1024);
            gload16(wql + bo, (char*)Bl + c * 1024);
        }
        asm volatile("s_waitcnt vmcnt(0)" ::: "memory");
        __syncthreads();
        bf16x8 ah[4], al[4], bh[4], bl[4];
        #pragma unroll
        for (int i = 0; i < 4; ++i) {
            int o = (wr + i * 16 + (lane & 15)) * 32 + (lane >> 4) * 8;
            ah[i] = *(bf16x8*)&Ah[o];
            al[i] = *(bf16x8*)&Al[o];
        }
        #pragma unroll
        for (int j = 0; j < 4; ++j) {
            int o = (wc + j * 16 + (lane & 15)) * 32 + (lane >> 4) * 8;
            bh[j] = *(bf16x8*)&Bh[o];
            bl[j] = *(bf16x8*)&Bl[o];
        }
        #pragma unroll
        for (int i = 0; i < 4; ++i)
            #pragma unroll
            for (int j = 0; j < 4; ++j) {
                acc[i][j] = __builtin_amdgcn_mfma_f32_16x16x32_bf16(ah[i], bh[j], acc[i][j], 0, 0, 0);
                acc[i][j] = __builtin_amdgcn_mfma_f32_16x16x32_bf16(ah[i], bl[j], acc[i][j], 0, 0, 0);
                acc[i][j] = __builtin_amdgcn_mfma_f32_16x16x32_bf16(al[i], bh[j], acc[i][j], 0, 0, 0);
            }
        __syncthreads();
    }

    const int h = (n0 + wc) >> 6;
    #pragma unroll
    for (int i = 0; i < 4; ++i)
        #pragma unroll
        for (int r = 0; r < 4; ++r) {
            int row = m0 + wr + i * 16 + (lane >> 4) * 4 + r;
            float s = 0.f;
            #pragma unroll
            for (int j = 0; j < 4; ++j) {
                int col = n0 + wc + j * 16 + (lane & 15);
                float val = acc[i][j][r] + bq[col];
                qbuf[(size_t)row * D_ + col] = f2b(val);
                s += fabsf(val);
            }
            s += __shfl_xor(s, 1);
            s += __shfl_xor(s, 2);
            s += __shfl_xor(s, 4);
            s += __shfl_xor(s, 8);
            if ((lane & 15) == 0) {
                int b = row >> 11, t = row & (T_ - 1);
                qnorm[((size_t)b * H_ + h) * T_ + t] = s;
            }
        }
}

// ---------------------------------------------------------------------------
// Top-38 per (b,h): single wave, register-resident, iterative argmax with
// lower-index tie-break.
// ---------------------------------------------------------------------------
__global__ __launch_bounds__(64) void topk_kernel(
    const float* __restrict__ qnorm, int* __restrict__ idxout)
{
    const int g = blockIdx.x;
    const int lane = threadIdx.x;
    float v[32];
    const float* src = qnorm + (size_t)g * T_ + lane * 32;
    #pragma unroll
    for (int i = 0; i < 32; i += 4) {
        float4 t = *(const float4*)(src + i);
        v[i] = t.x; v[i + 1] = t.y; v[i + 2] = t.z; v[i + 3] = t.w;
    }
    unsigned removed = 0;
    float lm; int li;
    #pragma unroll
    for (int it = 0; it < U_ + 1; ++it) {
        lm = -3e38f; li = 0;
        #pragma unroll
        for (int i = 0; i < 32; ++i) {
            bool ok = !((removed >> i) & 1u) && v[i] > lm;
            lm = ok ? v[i] : lm;
            li = ok ? i : li;
        }
        if (it == U_) break;
        float bm = lm; int bi = lane * 32 + li;
        #pragma unroll
        for (int off = 32; off; off >>= 1) {
            float om = __shfl_xor(bm, off);
            int   oi = __shfl_xor(bi, off);
            if (om > bm || (om == bm && oi < bi)) { bm = om; bi = oi; }
        }
        if (lane == 0) idxout[g * U_ + it] = bi;
        if ((bi >> 5) == lane) removed |= 1u << (bi & 31);
    }
}

// ---------------------------------------------------------------------------
// MFMA attention partials. Block = (g, c of 256 j); wave w owns 64 j
// (cw = c*4+w in 0..31). Swapped QK^T: S^T[j][u] = mfma(K, q). Softmax per
// u via in-reg + shfl_xor(16,32). P packed bf16 -> per-wave LDS -> read back
// as PV B-frags. PV: O^T[d][u] = mfma(V^T, P^T). Partials (m,l,o) per
// (g,cw,u).
// ---------------------------------------------------------------------------
__global__ __launch_bounds__(256) void attn_part(
    const short* __restrict__ qbuf, const short* __restrict__ kb,
    const short* __restrict__ vt, const int* __restrict__ idxb,
    float* __restrict__ pm, float* __restrict__ pl, float* __restrict__ po)
{
    __shared__ short qs[48 * 72];          // [u][d] stride 72
    __shared__ short pls[4][48 * 72];      // per-wave P [u][j] stride 72
    __shared__ int   sidx[48];
    const int bid = blockIdx.x;
    const int g = bid & 63;
    const int c = bid >> 6;
    const int b = g >> 4, h = g & 15;
    const int tid = threadIdx.x, wid = tid >> 6, lane = tid & 63;
    const int l15 = lane & 15, gr = lane >> 4;
    const int cw = c * 4 + wid;
    const int j0w = cw * 64;

    if (tid < 48) sidx[tid] = (tid < U_) ? idxb[g * U_ + tid] : 0;
    __syncthreads();
    for (int e = tid; e < 48 * 16; e += 256) {
        int u = e >> 4, d4 = e & 15;
        short4 v = make_short4(0, 0, 0, 0);
        if (u < U_)
            v = *(const short4*)(qbuf + ((size_t)b * T_ + sidx[u]) * D_ + h * HD_ + d4 * 4);
        *(short4*)&qs[u * 72 + d4 * 4] = v;
    }
    __syncthreads();

    int su[3];
    #pragma unroll
    for (int uf = 0; uf < 3; ++uf) su[uf] = sidx[uf * 16 + l15];

    // ---- S^T = K @ q^T ----
    f32x4 accs[3][4];
    #pragma unroll
    for (int uf = 0; uf < 3; ++uf)
        #pragma unroll
        for (int jf = 0; jf < 4; ++jf)
            accs[uf][jf] = (f32x4){0.f, 0.f, 0.f, 0.f};

    bf16x8 ka[4][2], qb[3][2];
    #pragma unroll
    for (int jf = 0; jf < 4; ++jf)
        #pragma unroll
        for (int ks = 0; ks < 2; ++ks)
            ka[jf][ks] = *(const bf16x8*)(kb + ((size_t)g * T_ + j0w + jf * 16 + l15) * HD_ + ks * 32 + gr * 8);
    #pragma unroll
    for (int uf = 0; uf < 3; ++uf)
        #pragma unroll
        for (int ks = 0; ks < 2; ++ks)
            qb[uf][ks] = *(bf16x8*)&qs[(uf * 16 + l15) * 72 + ks * 32 + gr * 8];

    #pragma unroll
    for (int uf = 0; uf < 3; ++uf)
        #pragma unroll
        for (int jf = 0; jf < 4; ++jf) {
            accs[uf][jf] = __builtin_amdgcn_mfma_f32_16x16x32_bf16(ka[jf][0], qb[uf][0], accs[uf][jf], 0, 0, 0);
            accs[uf][jf] = __builtin_amdgcn_mfma_f32_16x16x32_bf16(ka[jf][1], qb[uf][1], accs[uf][jf], 0, 0, 0);
        }

    // ---- mask + per-u softmax partial (over this wave's 64 j) ----
    #pragma unroll
    for (int uf = 0; uf < 3; ++uf) {
        float mm = -3e38f;
        #pragma unroll
        for (int jf = 0; jf < 4; ++jf)
            #pragma unroll
            for (int r = 0; r < 4; ++r) {
                int j = j0w + jf * 16 + gr * 4 + r;
                float s = accs[uf][jf][r] * 0.125f;
                s = (j <= su[uf]) ? s : -1e30f;
                accs[uf][jf][r] = s;
                mm = fmaxf(mm, s);
            }
        mm = fmaxf(mm, __shfl_xor(mm, 16));
        mm = fmaxf(mm, __shfl_xor(mm, 32));
        float ll = 0.f;
        #pragma unroll
        for (int jf = 0; jf < 4; ++jf)
            #pragma unroll
            for (int r = 0; r < 4; ++r) {
                float e = __expf(accs[uf][jf][r] - mm);
                accs[uf][jf][r] = e;
                ll += e;
            }
        ll += __shfl_xor(ll, 16);
        ll += __shfl_xor(ll, 32);
        if (gr == 0) {
            int u = uf * 16 + l15;
            if (u < U_) {
                pm[((size_t)g * NCW_ + cw) * U_ + u] = mm;
                pl[((size_t)g * NCW_ + cw) * U_ + u] = ll;
            }
        }
    }

    // ---- pack P to bf16, per-wave LDS [u][j] ----
    short* pw = &pls[wid][0];
    #pragma unroll
    for (int uf = 0; uf < 3; ++uf)
        #pragma unroll
        for (int jf = 0; jf < 4; ++jf) {
            uint2 wv;
            wv.x = pack2(accs[uf][jf][0], accs[uf][jf][1]);
            wv.y = pack2(accs[uf][jf][2], accs[uf][jf][3]);
            *(uint2*)&pw[(uf * 16 + l15) * 72 + jf * 16 + gr * 4] = wv;
        }

    // ---- PV: O^T[d][u] = V^T @ P^T ----
    bf16x8 va[4][2], pb[3][2];
    #pragma unroll
    for (int df = 0; df < 4; ++df)
        #pragma unroll
        for (int ks = 0; ks < 2; ++ks)
            va[df][ks] = *(const bf16x8*)(vt + ((size_t)g * HD_ + df * 16 + l15) * T_ + j0w + ks * 32 + gr * 8);
    #pragma unroll
    for (int uf = 0; uf < 3; ++uf)
        #pragma unroll
        for (int ks = 0; ks < 2; ++ks)
            pb[uf][ks] = *(bf16x8*)&pw[(uf * 16 + l15) * 72 + ks * 32 + gr * 8];

    f32x4 acco[4][3];
    #pragma unroll
    for (int df = 0; df < 4; ++df)
        #pragma unroll
        for (int uf = 0; uf < 3; ++uf)
            acco[df][uf] = (f32x4){0.f, 0.f, 0.f, 0.f};
    #pragma unroll
    for (int df = 0; df < 4; ++df)
        #pragma unroll
        for (int uf = 0; uf < 3; ++uf) {
            acco[df][uf] = __builtin_amdgcn_mfma_f32_16x16x32_bf16(va[df][0], pb[uf][0], acco[df][uf], 0, 0, 0);
            acco[df][uf] = __builtin_amdgcn_mfma_f32_16x16x32_bf16(va[df][1], pb[uf][1], acco[df][uf], 0, 0, 0);
        }

    #pragma unroll
    for (int df = 0; df < 4; ++df)
        #pragma unroll
        for (int uf = 0; uf < 3; ++uf) {
            int u = uf * 16 + l15;
            if (u < U_) {
                float4 o;
                o.x = acco[df][uf][0]; o.y = acco[df][uf][1];
                o.z = acco[df][uf][2]; o.w = acco[df][uf][3];
                *(float4*)(po + (((size_t)g * NCW_ + cw) * U_ + u) * HD_ + df * 16 + gr * 4) = o;
            }
        }
}

// ---------------------------------------------------------------------------
// Online merge of 32 chunk partials -> selo[g][u][d]
// ---------------------------------------------------------------------------
__global__ __launch_bounds__(256) void attn_combine(
    const float* __restrict__ pm, const float* __restrict__ pl,
    const float* __restrict__ po, float* __restrict__ selo)
{
    const int g = blockIdx.x;
    const int tid = threadIdx.x;
    const int ug = tid >> 6, d = tid & 63;
    for (int u = ug; u < U_; u += 4) {
        float m = -3e38f, l = 0.f, o = 0.f;
        for (int c = 0; c < NCW_; ++c) {
            float mc = pm[((size_t)g * NCW_ + c) * U_ + u];
            float lc = pl[((size_t)g * NCW_ + c) * U_ + u];
            float oc = po[(((size_t)g * NCW_ + c) * U_ + u) * HD_ + d];
            if (mc > m) {
                float w = __expf(m - mc);
                l = l * w + lc; o = o * w + oc; m = mc;
            } else {
                float w = __expf(mc - m);
                l += lc * w; o += oc * w;
            }
        }
        selo[((size_t)g * U_ + u) * HD_ + d] = o / l;
    }
}

// ---------------------------------------------------------------------------
__global__ __launch_bounds__(256) void fill_kernel(
    const float* __restrict__ bo, float* __restrict__ out)
{
    const size_t i = (size_t)blockIdx.x * 256 + threadIdx.x;   // float4 index
    float4 bv = *(const float4*)(bo + ((i & 255) << 2));
    *(float4*)(out + i * 4) = bv;
}

__global__ __launch_bounds__(256) void oproj_kernel(
    const float* __restrict__ selo, const int* __restrict__ idxb,
    const float* __restrict__ Wo, float* __restrict__ out)
{
    __shared__ float sel[64];
    const int blk = blockIdx.x;
    const int h = (blk / U_) % H_;
    const int b = blk / (U_ * H_);
    const int t = idxb[blk];
    const int tid = threadIdx.x;
    if (tid < 64) sel[tid] = selo[(size_t)blk * HD_ + tid];
    __syncthreads();
    float* orow = out + ((size_t)b * T_ + t) * D_;
    #pragma unroll
    for (int rep = 0; rep < 4; ++rep) {
        int n = tid + rep * 256;
        float c = 0.f;
        #pragma unroll 8
        for (int dd = 0; dd < 64; ++dd)
            c += sel[dd] * Wo[(size_t)(h * HD_ + dd) * D_ + n];
        atomicAdd(orow + n, c);
    }
}

// ---------------------------------------------------------------------------
extern "C" void kernel_launch(void* const* d_in, const int* in_sizes, int n_in,
                              void* d_out, int out_size, void* d_ws, size_t ws_size,
                              hipStream_t stream)
{
    const float* x  = (const float*)d_in[0];
    const float* Wq = (const float*)d_in[1];
    const float* bq = (const float*)d_in[2];
    const float* Wk = (const float*)d_in[3];
    const float* bk = (const float*)d_in[4];
    const float* Wv = (const float*)d_in[5];
    const float* bv = (const float*)d_in[6];
    const float* Wo = (const float*)d_in[7];
    const float* bo = (const float*)d_in[8];
    float* out = (float*)d_out;

    char* ws = (char*)d_ws;
    short* xh    = (short*)(ws);                        // 16,777,216
    short* xl    = (short*)(ws + 16777216);             // 16,777,216
    short* wqh   = (short*)(ws + 33554432);             //  2,097,152
    short* wql   = (short*)(ws + 35651584);             //  2,097,152
    short* wkvt  = (short*)(ws + 37748736);             //  4,194,304
    short* kb    = (short*)(ws + 41943040);             // 16,777,216
    short* vt    = (short*)(ws + 58720256);             // 16,777,216
    float* qnorm = (float*)(ws + 75497472);             //    524,288
    int*   idxb  = (int*)  (ws + 76021760);             //     16,384
    float* selo  = (float*)(ws + 76038144);             //    622,592
    short* qbuf  = (short*)(ws + 76660736);             // 16,777,216 (end 93,437,952)
    // partials overlay xh/xl (dead after the GEMMs):
    float* po    = (float*)(ws);                        // 19,922,944
    float* pm    = (float*)(ws + 19922944);             //    311,296
    float* pl    = (float*)(ws + 20234240);             //    311,296

    convx_kernel<<<M_ * D_ / 1024, 256, 0, stream>>>(x, xh, xl);
    convw_kernel<<<dim3(32, 32, 3), 256, 0, stream>>>(Wq, Wk, Wv, wqh, wql, wkvt);
    kv_gemm<<<dim3(M_ / 128, 16), 256, 0, stream>>>(xh, wkvt, bk, bv, kb, vt);
    q_gemm<<<dim3(M_ / 128, 8), 256, 0, stream>>>(xh, xl, wqh, wql, bq, qnorm, qbuf);
    topk_kernel<<<B_ * H_, 64, 0, stream>>>(qnorm, idxb);
    attn_part<<<64 * 8, 256, 0, stream>>>(qbuf, kb, vt, idxb, pm, pl, po);
    attn_combine<<<B_ * H_, 256, 0, stream>>>(pm, pl, po, selo);
    fill_kernel<<<(M_ * D_ / 4) / 256, 256, 0, stream>>>(bo, out);
    oproj_kernel<<<B_ * H_ * U_, 256, 0, stream>>>(selo, idxb, Wo, out);
}

// Round 5
// 239.549 us; speedup vs baseline: 1.3171x; 1.3171x over previous
//
#include <hip/hip_runtime.h>
#include <hip/hip_bf16.h>
#include <math.h>

#define B_  4
#define T_  2048
#define D_  1024
#define H_  16
#define HD_ 64
#define U_  38
#define M_  (B_*T_)   // 8192
#define NCW_ 32       // 64-j chunks per head

typedef __attribute__((ext_vector_type(8))) short bf16x8;
typedef __attribute__((ext_vector_type(4))) float f32x4;

__device__ __forceinline__ short f2b(float f) {
    __hip_bfloat16 b = __float2bfloat16(f);
    return *(short*)&b;
}
__device__ __forceinline__ float b2f(short s) {
    __hip_bfloat16 b = *(__hip_bfloat16*)&s;
    return __bfloat162float(b);
}
__device__ __forceinline__ unsigned pack2(float lo, float hi) {
    unsigned a = (unsigned short)f2b(lo);
    unsigned b = ((unsigned)(unsigned short)f2b(hi)) << 16;
    return a | b;
}

__device__ __forceinline__ void gload16(const void* g, void* l) {
    __builtin_amdgcn_global_load_lds(
        (const __attribute__((address_space(1))) unsigned int*)g,
        (__attribute__((address_space(3))) unsigned int*)l,
        16, 0, 0);
}

// ---------------------------------------------------------------------------
// x [8192][1024] fp32 -> xh, xl bf16 (hi + residual-lo split)
// ---------------------------------------------------------------------------
__global__ __launch_bounds__(256) void convx_kernel(
    const float* __restrict__ x, short* __restrict__ xh, short* __restrict__ xl)
{
    const size_t i = ((size_t)blockIdx.x * 256 + threadIdx.x) * 4;
    float4 v = *(const float4*)(x + i);
    short4 h, l;
    h.x = f2b(v.x); l.x = f2b(v.x - b2f(h.x));
    h.y = f2b(v.y); l.y = f2b(v.y - b2f(h.y));
    h.z = f2b(v.z); l.z = f2b(v.z - b2f(h.z));
    h.w = f2b(v.w); l.w = f2b(v.w - b2f(h.w));
    *(short4*)(xh + i) = h;
    *(short4*)(xl + i) = l;
}

// ---------------------------------------------------------------------------
// Transpose weights to [n][k] bf16. z=0: Wq -> wqh+wql. z=1: Wk. z=2: Wv.
// ---------------------------------------------------------------------------
__global__ __launch_bounds__(256) void convw_kernel(
    const float* __restrict__ Wq, const float* __restrict__ Wk, const float* __restrict__ Wv,
    short* __restrict__ wqh, short* __restrict__ wql, short* __restrict__ wkvt)
{
    __shared__ float tile[32][33];
    const int which = blockIdx.z;
    const float* W = which == 0 ? Wq : (which == 1 ? Wk : Wv);
    const int k0 = blockIdx.y * 32, n0 = blockIdx.x * 32;
    const int tx = threadIdx.x & 31, ty = threadIdx.x >> 5;
    #pragma unroll
    for (int r = ty; r < 32; r += 8)
        tile[r][tx] = W[(size_t)(k0 + r) * D_ + n0 + tx];
    __syncthreads();
    #pragma unroll
    for (int r = ty; r < 32; r += 8) {
        float v = tile[tx][r];                 // W[k0+tx][n0+r]
        size_t o = (size_t)(n0 + r) * D_ + k0 + tx;
        if (which == 0) {
            short h = f2b(v);
            wqh[o] = h;
            wql[o] = f2b(v - b2f(h));
        } else {
            wkvt[(size_t)(which - 1) * D_ * D_ + o] = f2b(v);
        }
    }
}

// ---------------------------------------------------------------------------
// K/V projection. K -> kb [g][t][d]; V -> vt [g][d][t] (transposed, so the
// attention PV step can read V^T fragments contiguously).
// ---------------------------------------------------------------------------
__global__ __launch_bounds__(256) void kv_gemm(
    const short* __restrict__ xh, const short* __restrict__ wkvt,
    const float* __restrict__ bk, const float* __restrict__ bv,
    short* __restrict__ kb, short* __restrict__ vt)
{
    __shared__ short As[128 * 32];
    __shared__ short Bs[128 * 32];
    const int tid = threadIdx.x, wid = tid >> 6, lane = tid & 63;
    const int m0 = blockIdx.x * 128;
    const int n0 = blockIdx.y * 128;
    const int wr = (wid >> 1) * 64, wc = (wid & 1) * 64;

    f32x4 acc[4][4];
    #pragma unroll
    for (int i = 0; i < 4; ++i)
        #pragma unroll
        for (int j = 0; j < 4; ++j)
            acc[i][j] = (f32x4){0.f, 0.f, 0.f, 0.f};

    const int srow = lane >> 2, scol = (lane & 3) * 8;

    for (int k0 = 0; k0 < D_; k0 += 32) {
        #pragma unroll
        for (int cc = 0; cc < 2; ++cc) {
            int c = wid + cc * 4;
            int r = c * 16 + srow;
            gload16(xh   + (size_t)(m0 + r) * D_ + k0 + scol, (char*)As + c * 1024);
            gload16(wkvt + (size_t)(n0 + r) * D_ + k0 + scol, (char*)Bs + c * 1024);
        }
        asm volatile("s_waitcnt vmcnt(0)" ::: "memory");
        __syncthreads();
        bf16x8 a[4], b[4];
        #pragma unroll
        for (int i = 0; i < 4; ++i)
            a[i] = *(bf16x8*)&As[(wr + i * 16 + (lane & 15)) * 32 + (lane >> 4) * 8];
        #pragma unroll
        for (int j = 0; j < 4; ++j)
            b[j] = *(bf16x8*)&Bs[(wc + j * 16 + (lane & 15)) * 32 + (lane >> 4) * 8];
        #pragma unroll
        for (int i = 0; i < 4; ++i)
            #pragma unroll
            for (int j = 0; j < 4; ++j)
                acc[i][j] = __builtin_amdgcn_mfma_f32_16x16x32_bf16(a[i], b[j], acc[i][j], 0, 0, 0);
        __syncthreads();
    }

    #pragma unroll
    for (int i = 0; i < 4; ++i)
        #pragma unroll
        for (int j = 0; j < 4; ++j)
            #pragma unroll
            for (int r = 0; r < 4; ++r) {
                int row = m0 + wr + i * 16 + (lane >> 4) * 4 + r;
                int col = n0 + wc + j * 16 + (lane & 15);
                int bb = row >> 11, t = row & (T_ - 1);
                float bias = (col < D_) ? bk[col] : bv[col - D_];
                float val = acc[i][j][r] + bias;
                int cc2 = col & (D_ - 1);
                int hh = cc2 >> 6, dd = cc2 & 63;
                if (col < D_)
                    kb[(((size_t)bb * H_ + hh) * T_ + t) * HD_ + dd] = f2b(val);
                else
                    vt[(((size_t)bb * H_ + hh) * HD_ + dd) * T_ + t] = f2b(val);
            }
}

// ---------------------------------------------------------------------------
// Q: 3-product split-bf16 GEMM (xh·wh + xh·wl + xl·wh), fp32 acc. Writes
// per-(b,h,t) L1 norm (fp32-accurate, for ranking) and q values (bf16).
// ---------------------------------------------------------------------------
__global__ __launch_bounds__(256) void q_gemm(
    const short* __restrict__ xh, const short* __restrict__ xl,
    const short* __restrict__ wqh, const short* __restrict__ wql,
    const float* __restrict__ bq, float* __restrict__ qnorm,
    short* __restrict__ qbuf)
{
    __shared__ short Ah[128 * 32], Al[128 * 32], Bh[128 * 32], Bl[128 * 32];
    const int tid = threadIdx.x, wid = tid >> 6, lane = tid & 63;
    const int m0 = blockIdx.x * 128;
    const int n0 = blockIdx.y * 128;
    const int wr = (wid >> 1) * 64, wc = (wid & 1) * 64;

    f32x4 acc[4][4];
    #pragma unroll
    for (int i = 0; i < 4; ++i)
        #pragma unroll
        for (int j = 0; j < 4; ++j)
            acc[i][j] = (f32x4){0.f, 0.f, 0.f, 0.f};

    const int srow = lane >> 2, scol = (lane & 3) * 8;

    for (int k0 = 0; k0 < D_; k0 += 32) {
        #pragma unroll
        for (int cc = 0; cc < 2; ++cc) {
            int c = wid + cc * 4;
            int r = c * 16 + srow;
            size_t ao = (size_t)(m0 + r) * D_ + k0 + scol;
            size_t bo = (size_t)(n0 + r) * D_ + k0 + scol;
            gload16(xh  + ao, (char*)Ah + c * 1024);
            gload16(xl  + ao, (char*)Al + c * 1024);
            gload16(wqh + bo, (char*)Bh + c * 1024);
            gload16(wql + bo, (char*)Bl + c * 1024);
        }
        asm volatile("s_waitcnt vmcnt(0)" ::: "memory");
        __syncthreads();
        bf16x8 ah[4], al[4], bh[4], bl[4];
        #pragma unroll
        for (int i = 0; i < 4; ++i) {
            int o = (wr + i * 16 + (lane & 15)) * 32 + (lane >> 4) * 8;
            ah[i] = *(bf16x8*)&Ah[o];
            al[i] = *(bf16x8*)&Al[o];
        }
        #pragma unroll
        for (int j = 0; j < 4; ++j) {
            int o = (wc + j * 16 + (lane & 15)) * 32 + (lane >> 4) * 8;
            bh[j] = *(bf16x8*)&Bh[o];
            bl[j] = *(bf16x8*)&Bl[o];
        }
        #pragma unroll
        for (int i = 0; i < 4; ++i)
            #pragma unroll
            for (int j = 0; j < 4; ++j) {
                acc[i][j] = __builtin_amdgcn_mfma_f32_16x16x32_bf16(ah[i], bh[j], acc[i][j], 0, 0, 0);
                acc[i][j] = __builtin_amdgcn_mfma_f32_16x16x32_bf16(ah[i], bl[j], acc[i][j], 0, 0, 0);
                acc[i][j] = __builtin_amdgcn_mfma_f32_16x16x32_bf16(al[i], bh[j], acc[i][j], 0, 0, 0);
            }
        __syncthreads();
    }

    const int h = (n0 + wc) >> 6;
    #pragma unroll
    for (int i = 0; i < 4; ++i)
        #pragma unroll
        for (int r = 0; r < 4; ++r) {
            int row = m0 + wr + i * 16 + (lane >> 4) * 4 + r;
            float s = 0.f;
            #pragma unroll
            for (int j = 0; j < 4; ++j) {
                int col = n0 + wc + j * 16 + (lane & 15);
                float val = acc[i][j][r] + bq[col];
                qbuf[(size_t)row * D_ + col] = f2b(val);
                s += fabsf(val);
            }
            s += __shfl_xor(s, 1);
            s += __shfl_xor(s, 2);
            s += __shfl_xor(s, 4);
            s += __shfl_xor(s, 8);
            if ((lane & 15) == 0) {
                int b = row >> 11, t = row & (T_ - 1);
                qnorm[((size_t)b * H_ + h) * T_ + t] = s;
            }
        }
}

// ---------------------------------------------------------------------------
// Top-38 per (b,h): single wave, register-resident, iterative argmax with
// lower-index tie-break.
// ---------------------------------------------------------------------------
__global__ __launch_bounds__(64) void topk_kernel(
    const float* __restrict__ qnorm, int* __restrict__ idxout)
{
    const int g = blockIdx.x;
    const int lane = threadIdx.x;
    float v[32];
    const float* src = qnorm + (size_t)g * T_ + lane * 32;
    #pragma unroll
    for (int i = 0; i < 32; i += 4) {
        float4 t = *(const float4*)(src + i);
        v[i] = t.x; v[i + 1] = t.y; v[i + 2] = t.z; v[i + 3] = t.w;
    }
    unsigned removed = 0;
    float lm; int li;
    #pragma unroll
    for (int it = 0; it < U_ + 1; ++it) {
        lm = -3e38f; li = 0;
        #pragma unroll
        for (int i = 0; i < 32; ++i) {
            bool ok = !((removed >> i) & 1u) && v[i] > lm;
            lm = ok ? v[i] : lm;
            li = ok ? i : li;
        }
        if (it == U_) break;
        float bm = lm; int bi = lane * 32 + li;
        #pragma unroll
        for (int off = 32; off; off >>= 1) {
            float om = __shfl_xor(bm, off);
            int   oi = __shfl_xor(bi, off);
            if (om > bm || (om == bm && oi < bi)) { bm = om; bi = oi; }
        }
        if (lane == 0) idxout[g * U_ + it] = bi;
        if ((bi >> 5) == lane) removed |= 1u << (bi & 31);
    }
}

// ---------------------------------------------------------------------------
// MFMA attention partials. Block = (g, c of 256 j); wave w owns 64 j
// (cw = c*4+w in 0..31). Swapped QK^T: S^T[j][u] = mfma(K, q). Softmax per
// u via in-reg + shfl_xor(16,32). P packed bf16 -> per-wave LDS -> read back
// as PV B-frags. PV: O^T[d][u] = mfma(V^T, P^T). Partials (m,l,o) per
// (g,cw,u).
// ---------------------------------------------------------------------------
__global__ __launch_bounds__(256) void attn_part(
    const short* __restrict__ qbuf, const short* __restrict__ kb,
    const short* __restrict__ vt, const int* __restrict__ idxb,
    float* __restrict__ pm, float* __restrict__ pl, float* __restrict__ po)
{
    __shared__ short qs[48 * 72];          // [u][d] stride 72
    __shared__ short pls[4][48 * 72];      // per-wave P [u][j] stride 72
    __shared__ int   sidx[48];
    const int bid = blockIdx.x;
    const int g = bid & 63;
    const int c = bid >> 6;
    const int b = g >> 4, h = g & 15;
    const int tid = threadIdx.x, wid = tid >> 6, lane = tid & 63;
    const int l15 = lane & 15, gr = lane >> 4;
    const int cw = c * 4 + wid;
    const int j0w = cw * 64;

    if (tid < 48) sidx[tid] = (tid < U_) ? idxb[g * U_ + tid] : 0;
    __syncthreads();
    for (int e = tid; e < 48 * 16; e += 256) {
        int u = e >> 4, d4 = e & 15;
        short4 v = make_short4(0, 0, 0, 0);
        if (u < U_)
            v = *(const short4*)(qbuf + ((size_t)b * T_ + sidx[u]) * D_ + h * HD_ + d4 * 4);
        *(short4*)&qs[u * 72 + d4 * 4] = v;
    }
    __syncthreads();

    int su[3];
    #pragma unroll
    for (int uf = 0; uf < 3; ++uf) su[uf] = sidx[uf * 16 + l15];

    // ---- S^T = K @ q^T ----
    f32x4 accs[3][4];
    #pragma unroll
    for (int uf = 0; uf < 3; ++uf)
        #pragma unroll
        for (int jf = 0; jf < 4; ++jf)
            accs[uf][jf] = (f32x4){0.f, 0.f, 0.f, 0.f};

    bf16x8 ka[4][2], qb[3][2];
    #pragma unroll
    for (int jf = 0; jf < 4; ++jf)
        #pragma unroll
        for (int ks = 0; ks < 2; ++ks)
            ka[jf][ks] = *(const bf16x8*)(kb + ((size_t)g * T_ + j0w + jf * 16 + l15) * HD_ + ks * 32 + gr * 8);
    #pragma unroll
    for (int uf = 0; uf < 3; ++uf)
        #pragma unroll
        for (int ks = 0; ks < 2; ++ks)
            qb[uf][ks] = *(bf16x8*)&qs[(uf * 16 + l15) * 72 + ks * 32 + gr * 8];

    #pragma unroll
    for (int uf = 0; uf < 3; ++uf)
        #pragma unroll
        for (int jf = 0; jf < 4; ++jf) {
            accs[uf][jf] = __builtin_amdgcn_mfma_f32_16x16x32_bf16(ka[jf][0], qb[uf][0], accs[uf][jf], 0, 0, 0);
            accs[uf][jf] = __builtin_amdgcn_mfma_f32_16x16x32_bf16(ka[jf][1], qb[uf][1], accs[uf][jf], 0, 0, 0);
        }

    // ---- mask + per-u softmax partial (over this wave's 64 j) ----
    #pragma unroll
    for (int uf = 0; uf < 3; ++uf) {
        float mm = -3e38f;
        #pragma unroll
        for (int jf = 0; jf < 4; ++jf)
            #pragma unroll
            for (int r = 0; r < 4; ++r) {
                int j = j0w + jf * 16 + gr * 4 + r;
                float s = accs[uf][jf][r] * 0.125f;
                s = (j <= su[uf]) ? s : -1e30f;
                accs[uf][jf][r] = s;
                mm = fmaxf(mm, s);
            }
        mm = fmaxf(mm, __shfl_xor(mm, 16));
        mm = fmaxf(mm, __shfl_xor(mm, 32));
        float ll = 0.f;
        #pragma unroll
        for (int jf = 0; jf < 4; ++jf)
            #pragma unroll
            for (int r = 0; r < 4; ++r) {
                float e = __expf(accs[uf][jf][r] - mm);
                accs[uf][jf][r] = e;
                ll += e;
            }
        ll += __shfl_xor(ll, 16);
        ll += __shfl_xor(ll, 32);
        if (gr == 0) {
            int u = uf * 16 + l15;
            if (u < U_) {
                pm[((size_t)g * NCW_ + cw) * U_ + u] = mm;
                pl[((size_t)g * NCW_ + cw) * U_ + u] = ll;
            }
        }
    }

    // ---- pack P to bf16, per-wave LDS [u][j] ----
    short* pw = &pls[wid][0];
    #pragma unroll
    for (int uf = 0; uf < 3; ++uf)
        #pragma unroll
        for (int jf = 0; jf < 4; ++jf) {
            uint2 wv;
            wv.x = pack2(accs[uf][jf][0], accs[uf][jf][1]);
            wv.y = pack2(accs[uf][jf][2], accs[uf][jf][3]);
            *(uint2*)&pw[(uf * 16 + l15) * 72 + jf * 16 + gr * 4] = wv;
        }

    // ---- PV: O^T[d][u] = V^T @ P^T ----
    bf16x8 va[4][2], pb[3][2];
    #pragma unroll
    for (int df = 0; df < 4; ++df)
        #pragma unroll
        for (int ks = 0; ks < 2; ++ks)
            va[df][ks] = *(const bf16x8*)(vt + ((size_t)g * HD_ + df * 16 + l15) * T_ + j0w + ks * 32 + gr * 8);
    #pragma unroll
    for (int uf = 0; uf < 3; ++uf)
        #pragma unroll
        for (int ks = 0; ks < 2; ++ks)
            pb[uf][ks] = *(bf16x8*)&pw[(uf * 16 + l15) * 72 + ks * 32 + gr * 8];

    f32x4 acco[4][3];
    #pragma unroll
    for (int df = 0; df < 4; ++df)
        #pragma unroll
        for (int uf = 0; uf < 3; ++uf)
            acco[df][uf] = (f32x4){0.f, 0.f, 0.f, 0.f};
    #pragma unroll
    for (int df = 0; df < 4; ++df)
        #pragma unroll
        for (int uf = 0; uf < 3; ++uf) {
            acco[df][uf] = __builtin_amdgcn_mfma_f32_16x16x32_bf16(va[df][0], pb[uf][0], acco[df][uf], 0, 0, 0);
            acco[df][uf] = __builtin_amdgcn_mfma_f32_16x16x32_bf16(va[df][1], pb[uf][1], acco[df][uf], 0, 0, 0);
        }

    #pragma unroll
    for (int df = 0; df < 4; ++df)
        #pragma unroll
        for (int uf = 0; uf < 3; ++uf) {
            int u = uf * 16 + l15;
            if (u < U_) {
                float4 o;
                o.x = acco[df][uf][0]; o.y = acco[df][uf][1];
                o.z = acco[df][uf][2]; o.w = acco[df][uf][3];
                *(float4*)(po + (((size_t)g * NCW_ + cw) * U_ + u) * HD_ + df * 16 + gr * 4) = o;
            }
        }
}

// ---------------------------------------------------------------------------
// Combine: grid (g, u-quad). Two-pass, dependency-free: max over 32 pm in
// registers, then 32 independent exp + weighted po loads. No serial chain.
// ---------------------------------------------------------------------------
__global__ __launch_bounds__(256) void attn_combine(
    const float* __restrict__ pm, const float* __restrict__ pl,
    const float* __restrict__ po, float* __restrict__ selo)
{
    const int g = blockIdx.x;
    const int u = blockIdx.y * 4 + (threadIdx.x >> 6);
    const int d = threadIdx.x & 63;
    if (u >= U_) return;

    const float* pmg = pm + (size_t)g * NCW_ * U_ + u;
    const float* plg = pl + (size_t)g * NCW_ * U_ + u;

    float mc[NCW_];
    #pragma unroll
    for (int c = 0; c < NCW_; ++c) mc[c] = pmg[(size_t)c * U_];
    float m = -3e38f;
    #pragma unroll
    for (int c = 0; c < NCW_; ++c) m = fmaxf(m, mc[c]);

    float w[NCW_];
    #pragma unroll
    for (int c = 0; c < NCW_; ++c) w[c] = __expf(mc[c] - m);

    float l = 0.f;
    #pragma unroll
    for (int c = 0; c < NCW_; ++c) l += plg[(size_t)c * U_] * w[c];

    float o = 0.f;
    #pragma unroll
    for (int c = 0; c < NCW_; ++c)
        o += po[(((size_t)g * NCW_ + c) * U_ + u) * HD_ + d] * w[c];

    selo[((size_t)g * U_ + u) * HD_ + d] = o / l;
}

// ---------------------------------------------------------------------------
__global__ __launch_bounds__(256) void fill_kernel(
    const float* __restrict__ bo, float* __restrict__ out)
{
    const size_t i = (size_t)blockIdx.x * 256 + threadIdx.x;   // float4 index
    float4 bv = *(const float4*)(bo + ((i & 255) << 2));
    *(float4*)(out + i * 4) = bv;
}

__global__ __launch_bounds__(256) void oproj_kernel(
    const float* __restrict__ selo, const int* __restrict__ idxb,
    const float* __restrict__ Wo, float* __restrict__ out)
{
    __shared__ float sel[64];
    const int blk = blockIdx.x;
    const int h = (blk / U_) % H_;
    const int b = blk / (U_ * H_);
    const int t = idxb[blk];
    const int tid = threadIdx.x;
    if (tid < 64) sel[tid] = selo[(size_t)blk * HD_ + tid];
    __syncthreads();
    float* orow = out + ((size_t)b * T_ + t) * D_;
    #pragma unroll
    for (int rep = 0; rep < 4; ++rep) {
        int n = tid + rep * 256;
        float c = 0.f;
        #pragma unroll 8
        for (int dd = 0; dd < 64; ++dd)
            c += sel[dd] * Wo[(size_t)(h * HD_ + dd) * D_ + n];
        atomicAdd(orow + n, c);
    }
}

// ---------------------------------------------------------------------------
extern "C" void kernel_launch(void* const* d_in, const int* in_sizes, int n_in,
                              void* d_out, int out_size, void* d_ws, size_t ws_size,
                              hipStream_t stream)
{
    const float* x  = (const float*)d_in[0];
    const float* Wq = (const float*)d_in[1];
    const float* bq = (const float*)d_in[2];
    const float* Wk = (const float*)d_in[3];
    const float* bk = (const float*)d_in[4];
    const float* Wv = (const float*)d_in[5];
    const float* bv = (const float*)d_in[6];
    const float* Wo = (const float*)d_in[7];
    const float* bo = (const float*)d_in[8];
    float* out = (float*)d_out;

    char* ws = (char*)d_ws;
    short* xh    = (short*)(ws);                        // 16,777,216
    short* xl    = (short*)(ws + 16777216);             // 16,777,216
    short* wqh   = (short*)(ws + 33554432);             //  2,097,152
    short* wql   = (short*)(ws + 35651584);             //  2,097,152
    short* wkvt  = (short*)(ws + 37748736);             //  4,194,304
    short* kb    = (short*)(ws + 41943040);             // 16,777,216
    short* vt    = (short*)(ws + 58720256);             // 16,777,216
    float* qnorm = (float*)(ws + 75497472);             //    524,288
    int*   idxb  = (int*)  (ws + 76021760);             //     16,384
    float* selo  = (float*)(ws + 76038144);             //    622,592
    short* qbuf  = (short*)(ws + 76660736);             // 16,777,216 (end 93,437,952)
    // partials overlay xh/xl (dead after the GEMMs):
    float* po    = (float*)(ws);                        // 19,922,944
    float* pm    = (float*)(ws + 19922944);             //    311,296
    float* pl    = (float*)(ws + 20234240);             //    311,296

    convx_kernel<<<M_ * D_ / 1024, 256, 0, stream>>>(x, xh, xl);
    convw_kernel<<<dim3(32, 32, 3), 256, 0, stream>>>(Wq, Wk, Wv, wqh, wql, wkvt);
    kv_gemm<<<dim3(M_ / 128, 16), 256, 0, stream>>>(xh, wkvt, bk, bv, kb, vt);
    q_gemm<<<dim3(M_ / 128, 8), 256, 0, stream>>>(xh, xl, wqh, wql, bq, qnorm, qbuf);
    topk_kernel<<<B_ * H_, 64, 0, stream>>>(qnorm, idxb);
    attn_part<<<64 * 8, 256, 0, stream>>>(qbuf, kb, vt, idxb, pm, pl, po);
    attn_combine<<<dim3(B_ * H_, (U_ + 3) / 4), 256, 0, stream>>>(pm, pl, po, selo);
    fill_kernel<<<(M_ * D_ / 4) / 256, 256, 0, stream>>>(bo, out);
    oproj_kernel<<<B_ * H_ * U_, 256, 0, stream>>>(selo, idxb, Wo, out);
}